// Round 1
// baseline (9557.562 us; speedup 1.0000x reference)
//
#include <hip/hip_runtime.h>
#include <stdint.h>

// FPS: B=8, N=131072, 3 coords, m=1024 selections.
// 32 blocks per batch, each owns N/32=4096 points fully resident in LDS.
// Per-batch spin barrier (device-scope atomics) once per iteration.

#define BATCHES 8
#define NPTS    131072
#define MSEL    1024
#define NBLK    32                 // blocks per batch
#define CHUNK   (NPTS / NBLK)      // 4096 points per block
#define NTH     256
#define NWAVE   (NTH / 64)

struct __align__(16) Partial {
    unsigned long long key;        // (f32 bits of best min_dist)<<32 | ~idx
    float x, y, z;
    unsigned int pad;
};

__global__ __launch_bounds__(NTH, 1) void fps_kernel(
    const float* __restrict__ pts,   // [B][N][3]
    float* __restrict__ out,         // [B*M] idx-as-float, then [B*M*3] xyz
    unsigned int* counters,          // per-batch monotonic barrier counters
    Partial* partials)               // [2][B][NBLK] double-buffered
{
    __shared__ float lx[CHUNK];
    __shared__ float ly[CHUNK];
    __shared__ float lz[CHUNK];
    __shared__ float md[CHUNK];
    __shared__ unsigned long long wkey[NWAVE];
    __shared__ float curs[4];

    const int bid   = blockIdx.x;
    const int b     = bid & (BATCHES - 1);   // batch -> same XCD for its 32 blocks
    const int blk   = bid / BATCHES;         // 0..NBLK-1 within batch
    const int tid   = threadIdx.x;
    const int gbase = blk * CHUNK;
    const float* bp = pts + (size_t)b * NPTS * 3;

    // One-time stage: chunk -> LDS (SoA), min_dist = BIG
    for (int j = tid; j < CHUNK; j += NTH) {
        const size_t gi = (size_t)(gbase + j) * 3;
        lx[j] = bp[gi + 0];
        ly[j] = bp[gi + 1];
        lz[j] = bp[gi + 2];
        md[j] = 1e10f;
    }

    // First selected point is index 0
    float cx = bp[0], cy = bp[1], cz = bp[2];
    if (blk == 0 && tid == 0) {
        out[b * MSEL] = 0.0f;
        float* oxyz = out + BATCHES * MSEL;
        oxyz[(size_t)(b * MSEL) * 3 + 0] = cx;
        oxyz[(size_t)(b * MSEL) * 3 + 1] = cy;
        oxyz[(size_t)(b * MSEL) * 3 + 2] = cz;
    }
    __syncthreads();

    unsigned int* cnt = counters + (size_t)b * 64;  // 256B apart per batch
    const int wv = tid >> 6;
    const int ln = tid & 63;

    for (int s = 1; s < MSEL; ++s) {
        // ---- update min_dist vs current point; track local best key ----
        unsigned long long bk = 0ull;
        for (int j = tid; j < CHUNK; j += NTH) {
            float dx = __fsub_rn(lx[j], cx);
            float dy = __fsub_rn(ly[j], cy);
            float dz = __fsub_rn(lz[j], cz);
            // plain mul/add, ((dx^2+dy^2)+dz^2) order: match numpy/XLA exactly
            float d  = __fadd_rn(__fadd_rn(__fmul_rn(dx, dx), __fmul_rn(dy, dy)),
                                 __fmul_rn(dz, dz));
            float nm = fminf(md[j], d);
            md[j] = nm;
            unsigned long long key =
                ((unsigned long long)__float_as_uint(nm) << 32)
                | (unsigned int)~(unsigned int)(gbase + j);
            bk = (bk > key) ? bk : key;
        }
        // wave max-reduce
        #pragma unroll
        for (int o = 32; o > 0; o >>= 1) {
            unsigned long long other = __shfl_xor(bk, o, 64);
            bk = (bk > other) ? bk : other;
        }
        if (ln == 0) wkey[wv] = bk;
        __syncthreads();

        // ---- block winner -> global partial, arrive at batch barrier ----
        if (tid == 0) {
            unsigned long long k0 = wkey[0];
            #pragma unroll
            for (int w = 1; w < NWAVE; ++w) k0 = (k0 > wkey[w]) ? k0 : wkey[w];
            const unsigned int gw = ~(unsigned int)k0;
            const int lj = (int)gw - gbase;
            Partial* dst = partials + ((s & 1) * (BATCHES * NBLK) + b * NBLK + blk);
            dst->key = k0;
            dst->x = lx[lj];
            dst->y = ly[lj];
            dst->z = lz[lj];
            // release orders the partial stores before the increment
            __hip_atomic_fetch_add(cnt, 1u, __ATOMIC_RELEASE, __HIP_MEMORY_SCOPE_AGENT);
        }

        // ---- wave 0: spin for all 32 blocks, reduce winners, broadcast ----
        if (wv == 0) {
            const unsigned int target = (unsigned int)NBLK * (unsigned int)s;
            unsigned int c;
            do {
                __builtin_amdgcn_s_sleep(1);
                c = __hip_atomic_load(cnt, __ATOMIC_ACQUIRE, __HIP_MEMORY_SCOPE_AGENT);
            } while (c < target);
            const Partial* pp = partials + ((s & 1) * (BATCHES * NBLK) + b * NBLK);
            unsigned long long k = 0ull;
            if (ln < NBLK) {
                k = __hip_atomic_load(&pp[ln].key, __ATOMIC_RELAXED, __HIP_MEMORY_SCOPE_AGENT);
            }
            #pragma unroll
            for (int o = 32; o > 0; o >>= 1) {
                unsigned long long other = __shfl_xor(k, o, 64);
                k = (k > other) ? k : other;
            }
            if (ln == 0) {
                const unsigned int gwin = ~(unsigned int)k;
                const int wblk = (int)(gwin / CHUNK);
                const unsigned int* wpx = (const unsigned int*)&pp[wblk].x;
                unsigned int ux = __hip_atomic_load(wpx + 0, __ATOMIC_RELAXED, __HIP_MEMORY_SCOPE_AGENT);
                unsigned int uy = __hip_atomic_load(wpx + 1, __ATOMIC_RELAXED, __HIP_MEMORY_SCOPE_AGENT);
                unsigned int uz = __hip_atomic_load(wpx + 2, __ATOMIC_RELAXED, __HIP_MEMORY_SCOPE_AGENT);
                float wx = __uint_as_float(ux);
                float wy = __uint_as_float(uy);
                float wz = __uint_as_float(uz);
                curs[0] = wx; curs[1] = wy; curs[2] = wz;
                if (blk == 0) {
                    out[b * MSEL + s] = (float)gwin;   // idx exact in fp32 (<2^24)
                    float* oxyz = out + BATCHES * MSEL;
                    oxyz[(size_t)(b * MSEL + s) * 3 + 0] = wx;
                    oxyz[(size_t)(b * MSEL + s) * 3 + 1] = wy;
                    oxyz[(size_t)(b * MSEL + s) * 3 + 2] = wz;
                }
            }
        }
        __syncthreads();
        cx = curs[0]; cy = curs[1]; cz = curs[2];
    }
}

extern "C" void kernel_launch(void* const* d_in, const int* in_sizes, int n_in,
                              void* d_out, int out_size, void* d_ws, size_t ws_size,
                              hipStream_t stream) {
    const float* pts = (const float*)d_in[0];
    float* out = (float*)d_out;

    // d_ws is re-poisoned 0xAA before every launch: zero the barrier counters.
    hipMemsetAsync(d_ws, 0, 4096, stream);
    unsigned int* counters = (unsigned int*)d_ws;
    Partial* partials = (Partial*)((char*)d_ws + 4096);

    fps_kernel<<<dim3(BATCHES * NBLK), dim3(NTH), 0, stream>>>(pts, out, counters, partials);
}

// Round 2
// 3175.571 us; speedup vs baseline: 3.0097x; 3.0097x over previous
//
#include <hip/hip_runtime.h>
#include <stdint.h>

// FPS: B=8, N=131072, 3 coords, m=1024.
// 32 blocks/batch; each thread OWNS 16 points in registers (xyz + min_dist).
// Cross-block sync per iteration via a single relaxed agent-scope u64 slot
// per block: value = distBits<<27 | (N-1-idx)<<10 | tag(=s&1023).
// Tag-in-payload + parity double-buffer => no fences, no counters, no
// acquire/release, no second read round. ws poison tag (0xAA.. -> 682)
// cannot alias the first-use tags (1,2), so no memset needed.

#define BATCHES 8
#define NPTS    131072
#define MSEL    1024
#define NBLK    32                 // blocks per batch
#define CHUNK   (NPTS / NBLK)      // 4096 points per block
#define NTH     256
#define PPT     (CHUNK / NTH)      // 16 points per thread (in registers)
#define NWAVE   (NTH / 64)

__global__ __launch_bounds__(NTH, 1) void fps_kernel(
    const float* __restrict__ pts,          // [B][N][3]
    float* __restrict__ out,                // [B*M] idx-as-float, then [B*M*3] xyz
    unsigned long long* __restrict__ slots) // [2][BATCHES][NBLK]
{
    __shared__ unsigned long long wkey[NWAVE];
    __shared__ float curs[4];

    const int bid   = blockIdx.x;
    const int b     = bid & (BATCHES - 1);   // batch -> same XCD heuristic
    const int blk   = bid / BATCHES;         // 0..NBLK-1 within batch
    const int tid   = threadIdx.x;
    const int gbase = blk * CHUNK;
    const float* bp = pts + (size_t)b * NPTS * 3;

    // Stage this thread's 16 points into registers (strided for coalescing).
    float px[PPT], py[PPT], pz[PPT], md[PPT];
    #pragma unroll
    for (int k = 0; k < PPT; ++k) {
        const int j = gbase + k * NTH + tid;
        const size_t gi = (size_t)j * 3;
        px[k] = bp[gi + 0];
        py[k] = bp[gi + 1];
        pz[k] = bp[gi + 2];
        md[k] = 1e10f;
    }
    // rel = NPTS-1-idx for this thread's k=0 point; k-th point: rel - k*NTH.
    const unsigned int relt = (unsigned int)(NPTS - 1) - (unsigned int)(gbase + tid);

    // First selected point is index 0.
    float cx = bp[0], cy = bp[1], cz = bp[2];
    if (blk == 0 && tid == 0) {
        out[b * MSEL] = 0.0f;
        float* oxyz = out + BATCHES * MSEL;
        oxyz[(size_t)(b * MSEL) * 3 + 0] = cx;
        oxyz[(size_t)(b * MSEL) * 3 + 1] = cy;
        oxyz[(size_t)(b * MSEL) * 3 + 2] = cz;
    }

    const int wv = tid >> 6;
    const int ln = tid & 63;

    for (int s = 1; s < MSEL; ++s) {
        // ---- register-resident min-dist update + local argmax key ----
        unsigned long long bk = 0ull;
        #pragma unroll
        for (int k = 0; k < PPT; ++k) {
            float dx = __fsub_rn(px[k], cx);
            float dy = __fsub_rn(py[k], cy);
            float dz = __fsub_rn(pz[k], cz);
            // plain mul/add, ((dx^2+dy^2)+dz^2) order: bit-match numpy
            float d  = __fadd_rn(__fadd_rn(__fmul_rn(dx, dx), __fmul_rn(dy, dy)),
                                 __fmul_rn(dz, dz));
            float nm = fminf(md[k], d);
            md[k] = nm;
            // key: dist bits (hi32) | (N-1-idx) (lo): max => largest dist,
            // ties -> smallest idx (np.argmax first-occurrence semantics)
            unsigned long long key =
                ((unsigned long long)__float_as_uint(nm) << 32)
                | (unsigned long long)(relt - (unsigned int)(k * NTH));
            bk = (bk > key) ? bk : key;
        }
        // wave max-reduce
        #pragma unroll
        for (int o = 32; o > 0; o >>= 1) {
            unsigned long long t = __shfl_xor(bk, o, 64);
            bk = (bk > t) ? bk : t;
        }
        if (ln == 0) wkey[wv] = bk;
        __syncthreads();

        if (wv == 0) {
            const unsigned int tag = (unsigned int)(s & 1023);
            // block winner -> slot (relaxed; payload is self-contained)
            if (ln == 0) {
                unsigned long long k0 = wkey[0];
                #pragma unroll
                for (int w = 1; w < NWAVE; ++w) k0 = (k0 > wkey[w]) ? k0 : wkey[w];
                const unsigned long long bits = k0 >> 32;           // dist bits
                const unsigned long long rel  = k0 & 0x1FFFFull;    // N-1-idx (17b)
                const unsigned long long sv   = (bits << 27) | (rel << 10) | tag;
                __hip_atomic_store(&slots[((size_t)(s & 1) * BATCHES + b) * NBLK + blk],
                                   sv, __ATOMIC_RELAXED, __HIP_MEMORY_SCOPE_AGENT);
            }
            // poll all NBLK slots of this batch (lanes 0..NBLK-1)
            const unsigned long long* sl =
                &slots[((size_t)(s & 1) * BATCHES + b) * NBLK];
            unsigned long long k = 0ull;
            for (;;) {
                if (ln < NBLK)
                    k = __hip_atomic_load(&sl[ln], __ATOMIC_RELAXED,
                                          __HIP_MEMORY_SCOPE_AGENT);
                const int ok = (ln >= NBLK) | ((unsigned int)(k & 1023ull) == tag);
                if (__all(ok)) break;
                __builtin_amdgcn_s_sleep(1);
            }
            // cross-block max reduce (keys already in registers)
            #pragma unroll
            for (int o = 32; o > 0; o >>= 1) {
                unsigned long long t = __shfl_xor(k, o, 64);
                k = (k > t) ? k : t;
            }
            const unsigned int widx =
                (unsigned int)(NPTS - 1) - (unsigned int)((k >> 10) & 0x1FFFFull);
            if (ln < 3) {
                const float v = bp[(size_t)widx * 3 + ln];
                curs[ln] = v;
                if (blk == 0)
                    out[BATCHES * MSEL + (size_t)(b * MSEL + s) * 3 + ln] = v;
            }
            if (ln == 0 && blk == 0) out[b * MSEL + s] = (float)widx;
        }
        __syncthreads();
        cx = curs[0]; cy = curs[1]; cz = curs[2];
    }
}

extern "C" void kernel_launch(void* const* d_in, const int* in_sizes, int n_in,
                              void* d_out, int out_size, void* d_ws, size_t ws_size,
                              hipStream_t stream) {
    const float* pts = (const float*)d_in[0];
    float* out = (float*)d_out;
    unsigned long long* slots = (unsigned long long*)d_ws;  // [2][8][32] u64 = 4KB

    fps_kernel<<<dim3(BATCHES * NBLK), dim3(NTH), 0, stream>>>(pts, out, slots);
}

// Round 3
// 2332.288 us; speedup vs baseline: 4.0979x; 1.3616x over previous
//
#include <hip/hip_runtime.h>
#include <stdint.h>

// FPS: B=8, N=131072, 3 coords, m=1024.
// 32 blocks/batch (bid%8==batch -> same XCD under round-robin dispatch);
// each thread owns 16 points in registers. Per-iteration cross-block sync:
//   wave0: store winner to L2-coherent slot (global_store sc0) and poll the
//          32 L2 slots (global_load sc0) -- intra-XCD L2 RTT, no IC trip.
//   wave1: posts the same winner to an agent-scope backup slot every iter.
//   wave0 falls back (sticky) to polling the backup slots after a bounded
//   number of L2 poll rounds -- safe under ANY block->XCD placement.
// Payload u64 = distBits<<27 | (N-1-idx)<<10 | tag(s). Tag-in-payload +
// parity double-buffer => no fences. ws 0xAA poison tag = 682, first-use
// tags are 1,2 => no aliasing, no memset needed.

#define BATCHES 8
#define NPTS    131072
#define MSEL    1024
#define NBLK    32                 // blocks per batch
#define CHUNK   (NPTS / NBLK)      // 4096 points per block
#define NTH     256
#define PPT     (CHUNK / NTH)      // 16 points per thread (registers)
#define NWAVE   (NTH / 64)
#define L2_TIMEOUT_ROUNDS 2000     // ~0.3ms one-time, then sticky fallback

__device__ __forceinline__ unsigned long long l2_load_u64(
    const unsigned long long* p) {
    unsigned long long v;
    asm volatile("global_load_dwordx2 %0, %1, off sc0\n\t"
                 "s_waitcnt vmcnt(0)"
                 : "=v"(v) : "v"(p) : "memory");
    return v;
}
__device__ __forceinline__ void l2_store_u64(unsigned long long* p,
                                             unsigned long long v) {
    asm volatile("global_store_dwordx2 %0, %1, off sc0"
                 :: "v"(p), "v"(v) : "memory");
}

__global__ __launch_bounds__(NTH, 1) void fps_kernel(
    const float* __restrict__ pts,            // [B][N][3]
    float* __restrict__ out,                  // [B*M] idx, then [B*M*3] xyz
    unsigned long long* __restrict__ l2slots, // [2][BATCHES][NBLK]
    unsigned long long* __restrict__ icslots) // [2][BATCHES][NBLK]
{
    __shared__ unsigned long long wkey[NWAVE];
    __shared__ float curs[4];

    const int bid   = blockIdx.x;
    const int b     = bid & (BATCHES - 1);
    const int blk   = bid / BATCHES;
    const int tid   = threadIdx.x;
    const int gbase = blk * CHUNK;
    const float* bp = pts + (size_t)b * NPTS * 3;

    // Stage 16 points/thread into registers (strided => coalesced).
    float px[PPT], py[PPT], pz[PPT], md[PPT];
    #pragma unroll
    for (int k = 0; k < PPT; ++k) {
        const int j = gbase + k * NTH + tid;
        const size_t gi = (size_t)j * 3;
        px[k] = bp[gi + 0];
        py[k] = bp[gi + 1];
        pz[k] = bp[gi + 2];
        md[k] = 1e10f;
    }
    const unsigned int relt = (unsigned int)(NPTS - 1) - (unsigned int)(gbase + tid);

    float cx = bp[0], cy = bp[1], cz = bp[2];
    if (blk == 0 && tid == 0) {
        out[b * MSEL] = 0.0f;
        float* oxyz = out + BATCHES * MSEL;
        oxyz[(size_t)(b * MSEL) * 3 + 0] = cx;
        oxyz[(size_t)(b * MSEL) * 3 + 1] = cy;
        oxyz[(size_t)(b * MSEL) * 3 + 2] = cz;
    }

    const int wv = tid >> 6;
    const int ln = tid & 63;
    bool useAgent = false;   // wave0-uniform sticky fallback flag

    for (int s = 1; s < MSEL; ++s) {
        // ---- register-resident min-dist update + local argmax key ----
        unsigned long long bk = 0ull;
        #pragma unroll
        for (int k = 0; k < PPT; ++k) {
            float dx = __fsub_rn(px[k], cx);
            float dy = __fsub_rn(py[k], cy);
            float dz = __fsub_rn(pz[k], cz);
            float d  = __fadd_rn(__fadd_rn(__fmul_rn(dx, dx), __fmul_rn(dy, dy)),
                                 __fmul_rn(dz, dz));
            float nm = fminf(md[k], d);
            md[k] = nm;
            unsigned long long key =
                ((unsigned long long)__float_as_uint(nm) << 32)
                | (unsigned long long)(relt - (unsigned int)(k * NTH));
            bk = (bk > key) ? bk : key;
        }
        #pragma unroll
        for (int o = 32; o > 0; o >>= 1) {
            unsigned long long t = __shfl_xor(bk, o, 64);
            bk = (bk > t) ? bk : t;
        }
        if (ln == 0) wkey[wv] = bk;
        __syncthreads();

        const unsigned int tag = (unsigned int)s;  // 1..1023, never 682-aliases
        const size_t slbase = ((size_t)(s & 1) * BATCHES + b) * NBLK;

        // ---- wave1: agent-scope backup publish (fire-and-forget) ----
        if (wv == 1 && ln == 0) {
            unsigned long long k0 = wkey[0];
            #pragma unroll
            for (int w = 1; w < NWAVE; ++w) k0 = (k0 > wkey[w]) ? k0 : wkey[w];
            const unsigned long long sv =
                ((k0 >> 32) << 27) | ((k0 & 0x1FFFFull) << 10) | tag;
            __hip_atomic_store(&icslots[slbase + blk], sv,
                               __ATOMIC_RELAXED, __HIP_MEMORY_SCOPE_AGENT);
        }

        if (wv == 0) {
            // block winner -> L2 slot (intra-XCD coherent via sc0)
            if (ln == 0) {
                unsigned long long k0 = wkey[0];
                #pragma unroll
                for (int w = 1; w < NWAVE; ++w) k0 = (k0 > wkey[w]) ? k0 : wkey[w];
                const unsigned long long sv =
                    ((k0 >> 32) << 27) | ((k0 & 0x1FFFFull) << 10) | tag;
                l2_store_u64(&l2slots[slbase + blk], sv);
            }
            // poll (L2 fast path with bounded rounds, sticky agent fallback)
            unsigned long long k = 0ull;
            if (!useAgent) {
                int r = 0;
                for (;;) {
                    if (ln < NBLK) k = l2_load_u64(&l2slots[slbase + ln]);
                    if (__all((ln >= NBLK) | ((unsigned int)(k & 1023ull) == tag)))
                        break;
                    if (++r >= L2_TIMEOUT_ROUNDS) { useAgent = true; break; }
                    __builtin_amdgcn_s_sleep(1);
                }
            }
            if (useAgent) {
                for (;;) {
                    if (ln < NBLK)
                        k = __hip_atomic_load(&icslots[slbase + ln],
                                              __ATOMIC_RELAXED,
                                              __HIP_MEMORY_SCOPE_AGENT);
                    if (__all((ln >= NBLK) | ((unsigned int)(k & 1023ull) == tag)))
                        break;
                    __builtin_amdgcn_s_sleep(1);
                }
            }
            // cross-block max (lanes >=32 hold 0 => 5 levels suffice)
            #pragma unroll
            for (int o = 16; o > 0; o >>= 1) {
                unsigned long long t = __shfl_xor(k, o, 64);
                k = (k > t) ? k : t;
            }
            const unsigned int widx =
                (unsigned int)(NPTS - 1) - (unsigned int)((k >> 10) & 0x1FFFFull);
            if (ln < 3) {
                const float v = bp[(size_t)widx * 3 + ln];
                curs[ln] = v;
                if (blk == 0)
                    out[BATCHES * MSEL + (size_t)(b * MSEL + s) * 3 + ln] = v;
            }
            if (ln == 0 && blk == 0) out[b * MSEL + s] = (float)widx;
        }
        __syncthreads();
        cx = curs[0]; cy = curs[1]; cz = curs[2];
    }
}

extern "C" void kernel_launch(void* const* d_in, const int* in_sizes, int n_in,
                              void* d_out, int out_size, void* d_ws, size_t ws_size,
                              hipStream_t stream) {
    const float* pts = (const float*)d_in[0];
    float* out = (float*)d_out;
    unsigned long long* l2slots = (unsigned long long*)d_ws;               // 4KB
    unsigned long long* icslots = (unsigned long long*)((char*)d_ws + 4096);

    fps_kernel<<<dim3(BATCHES * NBLK), dim3(NTH), 0, stream>>>(
        pts, out, l2slots, icslots);
}

// Round 4
// 2249.454 us; speedup vs baseline: 4.2488x; 1.0368x over previous
//
#include <hip/hip_runtime.h>
#include <stdint.h>

// FPS: B=8, N=131072, 3 coords, m=1024.
// 32 blocks/batch (bid%8 -> same XCD under round-robin dispatch); 16 pts/thread
// in registers; xyz mirrored in LDS for winner extraction.
// Per-iteration sync: block winner (key + xyz) published to an L2-coherent
// 24B payload in a 128B-padded slot (global sc0); wave0 lanes 0..31 poll,
// each lane stops loading once its slot's tags match; 5-level shfl butterfly
// carries key+xyz so NO global fetch is needed after detection.
// Group A (dwordx4, one 16B transaction): [distBits, rel<<10|tag, x, y]
// Group B (dwordx2, one  8B transaction): [z, s]
// Each group self-tagged => tear-safe under relaxed ordering.
// Agent-scope key-only backup slots (wave1, every iter) + sticky timeout
// fallback keep the kernel correct under ANY block->XCD placement.
// 0xAA ws poison: tagA=682 vs first-use tags 1,2; tagB=0xAAAAAAAA != s. Safe.

#define BATCHES 8
#define NPTS    131072
#define MSEL    1024
#define NBLK    32                 // blocks per batch
#define CHUNK   (NPTS / NBLK)      // 4096 points per block
#define NTH     256
#define PPT     (CHUNK / NTH)      // 16 points per thread (registers)
#define NWAVE   (NTH / 64)
#define L2_TIMEOUT_ROUNDS 2000     // ~0.3ms one-time, then sticky agent path

typedef unsigned int       u32;
typedef unsigned long long u64;
typedef u32 u32x4 __attribute__((ext_vector_type(4)));
typedef u32 u32x2 __attribute__((ext_vector_type(2)));

__device__ __forceinline__ void l2_store_slot(void* p, u32x4 a, u32x2 b) {
    asm volatile("global_store_dwordx4 %0, %1, off sc0\n\t"
                 "global_store_dwordx2 %2, %3, off sc0"
                 :: "v"((u32*)p), "v"(a), "v"(((u32*)p) + 4), "v"(b)
                 : "memory");
}
__device__ __forceinline__ void l2_load_slot(const void* p, u32x4& a, u32x2& b) {
    u32x4 ra; u32x2 rb;
    asm volatile("global_load_dwordx4 %0, %2, off sc0\n\t"
                 "global_load_dwordx2 %1, %3, off sc0\n\t"
                 "s_waitcnt vmcnt(0)"
                 : "=&v"(ra), "=&v"(rb)
                 : "v"((const u32*)p), "v"(((const u32*)p) + 4)
                 : "memory");
    a = ra; b = rb;
}

__global__ __launch_bounds__(NTH, 1) void fps_kernel(
    const float* __restrict__ pts,      // [B][N][3]
    float* __restrict__ out,            // [B*M] idx-as-float, then [B*M*3] xyz
    char* __restrict__ l2base,          // [2][BATCHES][NBLK] x pad bytes
    u64*  __restrict__ icslots,         // [2][BATCHES][NBLK] key-only backup
    int pad)                            // slot padding in bytes (128 or 32)
{
    __shared__ float lx[CHUNK];
    __shared__ float ly[CHUNK];
    __shared__ float lz[CHUNK];
    __shared__ u64 wkey[NWAVE];
    __shared__ float curs[4];

    const int bid   = blockIdx.x;
    const int b     = bid & (BATCHES - 1);
    const int blk   = bid / BATCHES;
    const int tid   = threadIdx.x;
    const int gbase = blk * CHUNK;
    const float* bp = pts + (size_t)b * NPTS * 3;

    // Stage 16 points/thread into registers + LDS xyz mirror.
    float px[PPT], py[PPT], pz[PPT], md[PPT];
    #pragma unroll
    for (int k = 0; k < PPT; ++k) {
        const int j = k * NTH + tid;
        const size_t gi = (size_t)(gbase + j) * 3;
        px[k] = bp[gi + 0];
        py[k] = bp[gi + 1];
        pz[k] = bp[gi + 2];
        md[k] = 1e10f;
        lx[j] = px[k]; ly[j] = py[k]; lz[j] = pz[k];
    }
    const u32 relt = (u32)(NPTS - 1) - (u32)(gbase + tid);

    float cx = bp[0], cy = bp[1], cz = bp[2];
    if (blk == 0 && tid == 0) {
        out[b * MSEL] = 0.0f;
        float* oxyz = out + BATCHES * MSEL;
        oxyz[(size_t)(b * MSEL) * 3 + 0] = cx;
        oxyz[(size_t)(b * MSEL) * 3 + 1] = cy;
        oxyz[(size_t)(b * MSEL) * 3 + 2] = cz;
    }
    __syncthreads();   // LDS mirror visible to lane0 winner extraction

    const int wv = tid >> 6;
    const int ln = tid & 63;
    bool useAgent = false;

    for (int s = 1; s < MSEL; ++s) {
        // ---- min-dist update + local argmax; key = distBits<<17 | rel ----
        u64 bk = 0ull;
        #pragma unroll
        for (int k = 0; k < PPT; ++k) {
            float dx = __fsub_rn(px[k], cx);
            float dy = __fsub_rn(py[k], cy);
            float dz = __fsub_rn(pz[k], cz);
            float d  = __fadd_rn(__fadd_rn(__fmul_rn(dx, dx), __fmul_rn(dy, dy)),
                                 __fmul_rn(dz, dz));
            float nm = fminf(md[k], d);
            md[k] = nm;
            u64 key = ((u64)__float_as_uint(nm) << 17)
                    | (u64)(relt - (u32)(k * NTH));
            bk = (bk > key) ? bk : key;
        }
        #pragma unroll
        for (int o = 32; o > 0; o >>= 1) {
            u64 t = __shfl_xor(bk, o, 64);
            bk = (bk > t) ? bk : t;
        }
        if (ln == 0) wkey[wv] = bk;
        __syncthreads();

        const u32 tag = (u32)s;                    // 1..1023
        char* base = l2base + ((size_t)(s & 1) * BATCHES + b) * NBLK * (size_t)pad;
        const size_t icb = ((size_t)(s & 1) * BATCHES + b) * NBLK;

        // ---- wave1: agent-scope key-only backup publish ----
        if (wv == 1 && ln == 0) {
            u64 k0 = wkey[0];
            #pragma unroll
            for (int w = 1; w < NWAVE; ++w) k0 = (k0 > wkey[w]) ? k0 : wkey[w];
            const u64 sv = ((k0 >> 17) << 27) | ((k0 & 0x1FFFFull) << 10) | tag;
            __hip_atomic_store(&icslots[icb + blk], sv,
                               __ATOMIC_RELAXED, __HIP_MEMORY_SCOPE_AGENT);
        }

        if (wv == 0) {
            // ---- publish: block winner key + xyz (from LDS mirror) ----
            if (ln == 0) {
                u64 k0 = wkey[0];
                #pragma unroll
                for (int w = 1; w < NWAVE; ++w) k0 = (k0 > wkey[w]) ? k0 : wkey[w];
                const u32 rel = (u32)(k0 & 0x1FFFFull);
                const u32 db  = (u32)(k0 >> 17);
                const int j   = (int)((u32)(NPTS - 1) - rel) - gbase;
                u32x4 a; u32x2 bg;
                a.x = db; a.y = (rel << 10) | tag;
                a.z = __float_as_uint(lx[j]); a.w = __float_as_uint(ly[j]);
                bg.x = __float_as_uint(lz[j]); bg.y = tag;
                l2_store_slot(base + (size_t)blk * pad, a, bg);
            }
            // ---- poll: per-lane slot, stop loading once fresh ----
            u64 k = 0ull; float x = 0.f, y = 0.f, z = 0.f;
            if (!useAgent) {
                u32x4 A; u32x2 Bv; bool done = false;
                int r = 0;
                for (;;) {
                    if (ln < NBLK && !done) {
                        l2_load_slot(base + (size_t)ln * pad, A, Bv);
                        done = ((A.y & 1023u) == tag) & (Bv.y == tag);
                    }
                    if (__all((ln >= NBLK) | done)) break;
                    if (++r >= L2_TIMEOUT_ROUNDS) { useAgent = true; break; }
                    __builtin_amdgcn_s_sleep(1);
                }
                if (!useAgent && ln < NBLK) {
                    k = ((u64)A.x << 17) | (u64)(A.y >> 10);
                    x = __uint_as_float(A.z);
                    y = __uint_as_float(A.w);
                    z = __uint_as_float(Bv.x);
                }
            }
            if (useAgent) {
                // rare path: key-only agent slots, xyz re-fetched from pts
                u64 ak = 0ull;
                for (;;) {
                    if (ln < NBLK)
                        ak = __hip_atomic_load(&icslots[icb + ln],
                                               __ATOMIC_RELAXED,
                                               __HIP_MEMORY_SCOPE_AGENT);
                    if (__all((ln >= NBLK) | ((u32)(ak & 1023ull) == tag)))
                        break;
                    __builtin_amdgcn_s_sleep(1);
                }
                #pragma unroll
                for (int o = 16; o > 0; o >>= 1) {
                    u64 t = __shfl_xor(ak, o, 64);
                    ak = (ak > t) ? ak : t;
                }
                const u32 widx = (u32)(NPTS - 1) - (u32)((ak >> 10) & 0x1FFFFull);
                if (ln < 3) {
                    const float v = bp[(size_t)widx * 3 + ln];
                    curs[ln] = v;
                    if (blk == 0)
                        out[BATCHES * MSEL + (size_t)(b * MSEL + s) * 3 + ln] = v;
                }
                if (ln == 0 && blk == 0) out[b * MSEL + s] = (float)widx;
            } else {
                // ---- cross-block argmax carrying xyz payload ----
                #pragma unroll
                for (int o = 16; o > 0; o >>= 1) {
                    u64 kk = __shfl_xor(k, o, 64);
                    float xx = __shfl_xor(x, o, 64);
                    float yy = __shfl_xor(y, o, 64);
                    float zz = __shfl_xor(z, o, 64);
                    const bool p = kk > k;
                    k = p ? kk : k;
                    x = p ? xx : x;
                    y = p ? yy : y;
                    z = p ? zz : z;
                }
                if (ln == 0) {
                    const u32 widx = (u32)(NPTS - 1) - (u32)(k & 0x1FFFFull);
                    curs[0] = x; curs[1] = y; curs[2] = z;
                    if (blk == 0) {
                        out[b * MSEL + s] = (float)widx;
                        float* oxyz = out + BATCHES * MSEL;
                        oxyz[(size_t)(b * MSEL + s) * 3 + 0] = x;
                        oxyz[(size_t)(b * MSEL + s) * 3 + 1] = y;
                        oxyz[(size_t)(b * MSEL + s) * 3 + 2] = z;
                    }
                }
            }
        }
        __syncthreads();
        cx = curs[0]; cy = curs[1]; cz = curs[2];
    }
}

extern "C" void kernel_launch(void* const* d_in, const int* in_sizes, int n_in,
                              void* d_out, int out_size, void* d_ws, size_t ws_size,
                              hipStream_t stream) {
    const float* pts = (const float*)d_in[0];
    float* out = (float*)d_out;

    // 128B pad (one L2 line per block slot) if workspace allows, else 32B.
    const int pad = (ws_size >= (size_t)(2 * BATCHES * NBLK * 128 + 4096))
                        ? 128 : 32;
    char* l2base = (char*)d_ws;
    u64* icslots = (u64*)((char*)d_ws + (size_t)2 * BATCHES * NBLK * pad);

    fps_kernel<<<dim3(BATCHES * NBLK), dim3(NTH), 0, stream>>>(
        pts, out, l2base, icslots, pad);
}